// Round 5
// baseline (458.711 us; speedup 1.0000x reference)
//
#include <hip/hip_runtime.h>
#include <hip/hip_bf16.h>
#include <math.h>

// ---------- types ----------
typedef __attribute__((ext_vector_type(8))) short          short8;   // 8 bf16 (MFMA frag)
typedef __attribute__((ext_vector_type(8))) unsigned short u16x8;    // 16B chunk
typedef __attribute__((ext_vector_type(2))) unsigned int   u32x2;    // 8B chunk
typedef __attribute__((ext_vector_type(4))) float          f32x4;    // MFMA acc

#define MFMA_BF16(a, b, c) __builtin_amdgcn_mfma_f32_16x16x32_bf16((a), (b), (c), 0, 0, 0)

// async global->LDS, 16B per lane; LDS dst = wave-uniform base + lane*16
#define GLOAD_LDS16(gp, lp)                                        \
  __builtin_amdgcn_global_load_lds(                                \
      (const __attribute__((address_space(1))) void*)(gp),         \
      (__attribute__((address_space(3))) void*)(lp), 16, 0, 0)

// B=1, HID=1024, NH=16, D=64, S=8192, TILE=128, NTILE=64, 12 kv tiles/q tile
// Inputs fp32, output fp32 (verified rounds 1/5).

__device__ __forceinline__ unsigned short f2bf(float f) {
  union { float f; unsigned int u; } v; v.f = f;
  unsigned int r = v.u + 0x7fffu + ((v.u >> 16) & 1u);   // RNE
  return (unsigned short)(r >> 16);
}
// pack two positive floats to bf16 pair, round-half-up (P in (0, ~500])
// one v_perm_b32 replaces shr/and/or: result = {bf(b), bf(a)} (a in low 16)
__device__ __forceinline__ unsigned int pack2bf(float a, float b) {
  union { float f; unsigned int u; } x, y; x.f = a; y.f = b;
  return __builtin_amdgcn_perm(y.u + 0x8000u, x.u + 0x8000u, 0x07060302u);
}

// tile-order row r -> natural sequence index s
__device__ __forceinline__ int row_to_seq(int r) {
  int tile = r >> 7, pos = r & 127;
  int ntt = tile >> 4, nth = (tile >> 2) & 3, ntw = tile & 3;
  int tt  = pos >> 6,  th  = (pos >> 3) & 7,  tw  = pos & 7;
  return ((ntt * 2 + tt) << 10) | ((nth * 8 + th) << 5) | (ntw * 8 + tw);
}

// ---------- kernel 1: permute hidden_states rows into tile order (+cast fp32->bf16) ----------
__global__ __launch_bounds__(256) void permute_hs(const float* __restrict__ in,
                                                  unsigned short* __restrict__ out) {
  int cid = blockIdx.x * 256 + threadIdx.x;          // 1,048,576 chunks of 8 elems
  int r = cid >> 7, c = (cid & 127) * 8;
  int s = row_to_seq(r);
  const float* f = in + (size_t)s * 1024 + c;
  u16x8 v;
#pragma unroll
  for (int j = 0; j < 8; ++j) v[j] = f2bf(f[j]);
  *(u16x8*)(out + (size_t)r * 1024 + c) = v;
}

// ---------- kernel 2: transpose the 4 weight matrices [K][N] -> [N][K] (+cast) ----------
__global__ __launch_bounds__(256) void transpose_w(const float* __restrict__ w0,
                                                   const float* __restrict__ w1,
                                                   const float* __restrict__ w2,
                                                   const float* __restrict__ w3,
                                                   unsigned short* __restrict__ out) {
  __shared__ unsigned short Lt[64 * 68];             // [n][k] tile, pad 68
  int m = blockIdx.y;
  const float* W = (m == 0) ? w0 : (m == 1) ? w1 : (m == 2) ? w2 : w3;
  unsigned short* O = out + (size_t)m * 1048576;
  int k0 = (blockIdx.x >> 4) * 64, n0 = (blockIdx.x & 15) * 64;
  int tid = threadIdx.x;
#pragma unroll
  for (int i = 0; i < 2; ++i) {
    int cid = i * 256 + tid;
    int kr = cid >> 3, c = cid & 7;
    const float* f = W + (size_t)(k0 + kr) * 1024 + n0 + c * 8;
#pragma unroll
    for (int j = 0; j < 8; ++j) Lt[(c * 8 + j) * 68 + kr] = f2bf(f[j]);
  }
  __syncthreads();
#pragma unroll
  for (int i = 0; i < 2; ++i) {
    int cid = i * 256 + tid;
    int nr = cid >> 3, c = cid & 7;
    u16x8 v;
#pragma unroll
    for (int j = 0; j < 8; ++j) v[j] = Lt[nr * 68 + c * 8 + j];
    *(u16x8*)(O + (size_t)(n0 + nr) * 1024 + k0 + c * 8) = v;
  }
}

// ---------- gemm_bt: C[M][1024] = (A[M][1024] * Bt[1024][1024]^T) * scale ----------
// 128x128 block tile, BK=64, 4 waves (2x2 of 64x64), XOR-8 swizzled LDS,
// global_load_lds(16B) staging. OUT_F32: final output writes float.
template <int SCATTER, int OUT_F32>
__device__ __forceinline__ void gemm_bt_body(const unsigned short* __restrict__ A,
                                             const unsigned short* __restrict__ Bt,
                                             void* __restrict__ Cv,
                                             int row0, int col0, float scale) {
  __shared__ unsigned short As[128 * 64];
  __shared__ unsigned short Bs[128 * 64];
  const int tid  = threadIdx.x;
  const int lane = tid & 63, w = tid >> 6;
  const int quad = lane >> 4, lm = lane & 15;
  const int wr = (w >> 1) * 64, wc = (w & 1) * 64;
  f32x4 acc[4][4] = {};
  for (int kt = 0; kt < 16; ++kt) {
    const int k0 = kt * 64;
    __syncthreads();
#pragma unroll
    for (int i = 0; i < 4; ++i) {
      int cid = i * 256 + tid;
      int r = cid >> 3, c = cid & 7;
      int cg = c ^ (r & 7);                          // swizzle on SOURCE address
      int base = (i * 256 + (tid & 192)) * 8;        // wave-uniform LDS dst (u16)
      GLOAD_LDS16(A  + (size_t)(row0 + r) * 1024 + k0 + cg * 8, As + base);
      GLOAD_LDS16(Bt + (size_t)(col0 + r) * 1024 + k0 + cg * 8, Bs + base);
    }
    __syncthreads();
#pragma unroll
    for (int kh = 0; kh < 2; ++kh) {
      short8 af[4], bf[4];
#pragma unroll
      for (int t = 0; t < 4; ++t) {
        int ca = (kh * 4 + quad) ^ (lm & 7);
        af[t] = *(const short8*)(As + (wr + t * 16 + lm) * 64 + ca * 8);
        bf[t] = *(const short8*)(Bs + (wc + t * 16 + lm) * 64 + ca * 8);
      }
#pragma unroll
      for (int rt = 0; rt < 4; ++rt)
#pragma unroll
        for (int ct = 0; ct < 4; ++ct)
          acc[rt][ct] = MFMA_BF16(af[rt], bf[ct], acc[rt][ct]);
    }
  }
#pragma unroll
  for (int rt = 0; rt < 4; ++rt)
#pragma unroll
    for (int ct = 0; ct < 4; ++ct)
#pragma unroll
      for (int g = 0; g < 4; ++g) {
        int R  = row0 + wr + rt * 16 + quad * 4 + g;
        int Cc = col0 + wc + ct * 16 + lm;
        int Rs = SCATTER ? row_to_seq(R) : R;
        float vv = acc[rt][ct][g] * scale;
        if (OUT_F32) ((float*)Cv)[(size_t)Rs * 1024 + Cc] = vv;
        else ((unsigned short*)Cv)[(size_t)Rs * 1024 + Cc] = f2bf(vv);
      }
}

__global__ __launch_bounds__(256) void gemm_qkv(const unsigned short* __restrict__ A,
                                                const unsigned short* __restrict__ Wt,
                                                unsigned short* __restrict__ QKV) {
  // fold softmax scale (1/8)*log2(e) into Q so attn's exp2 needs no multiply
  float scale = (blockIdx.z == 0) ? 0.18033688011112042f : 1.0f;
  gemm_bt_body<0, 0>(A, Wt + (size_t)blockIdx.z * 1048576,
                     QKV + (size_t)blockIdx.z * 8388608,
                     blockIdx.y * 128, blockIdx.x * 128, scale);
}

__global__ __launch_bounds__(256) void gemm_out(const unsigned short* __restrict__ A,
                                                const unsigned short* __restrict__ Wt,
                                                float* __restrict__ Cout) {
  gemm_bt_body<1, 1>(A, Wt, Cout, blockIdx.y * 128, blockIdx.x * 128, 1.0f);
}

// ---------- kernel: V [8192][16*64] (tile rows) -> Vt [16][64][8192] ----------
__global__ __launch_bounds__(256) void transpose_v(const unsigned short* __restrict__ V,
                                                   unsigned short* __restrict__ Vt) {
  __shared__ unsigned short Lt[64 * 136];            // [d][r] tile, pad 136
  int kt = blockIdx.x, h = blockIdx.y, tid = threadIdx.x;
#pragma unroll
  for (int i = 0; i < 4; ++i) {
    int cid = i * 256 + tid;                         // 1024 chunks
    int r = cid >> 3, c = cid & 7;
    u16x8 v = *(const u16x8*)(V + (size_t)(kt * 128 + r) * 1024 + h * 64 + c * 8);
#pragma unroll
    for (int j = 0; j < 8; ++j) Lt[(c * 8 + j) * 136 + r] = v[j];
  }
  __syncthreads();
#pragma unroll
  for (int i = 0; i < 4; ++i) {
    int cid = i * 256 + tid;
    int d = cid >> 4, c = cid & 15;
    u16x8 v = *(const u16x8*)(Lt + d * 136 + c * 8);
    *(u16x8*)(Vt + (size_t)(h * 64 + d) * 8192 + kt * 128 + c * 8) = v;
  }
}

// ---------- attention: one block per (head, q-tile PAIR), 512 threads (8 waves) ----------
// Key fact: kt0 = min(max(ntt,1),2)-1 maps ntt {0,1}->0 and {2,3}->1, so q-tiles
// (2p, nth, ntw) and (2p+1, nth, ntw) have IDENTICAL 12-tile kv windows. One block
// processes both: K/V staging+HBM traffic halves per unit work, and each wave gets
// two independent QK^T->exp2->PV chains (ILP against the dependency stall seen in
// rounds 2/4: MfmaUtil 21 / VALU 49 / ~30% idle).
// Schedule per iter (from round 2, best so far): V[it] issued at top (drained at
// mid barrier, hidden under 2x QK^T+exp2); K[it+1] issued after mid barrier
// (drained at end barrier, hidden under 2x PV). Pb uses round-2's half-row layout
// (quartering regressed: conflicts 2x). LDS: Ks 16 + Vs 16 + Pb 2x16 = 64 KB ->
// 2 blocks/CU; grid 512 = exactly 2/CU, zero tail. (512,4) caps VGPR at 128
// (round 3 lesson: min-waves=8 forces VGPR=32 and catastrophic spills).
__global__ __launch_bounds__(512, 4) void attn(const unsigned short* __restrict__ Q,
                                               const unsigned short* __restrict__ K,
                                               const unsigned short* __restrict__ Vt,
                                               unsigned short* __restrict__ O) {
  __shared__ unsigned short Ks[128 * 64];            // 16 KB [kv][d], swizzled
  __shared__ unsigned short Vs[64 * 128];            // 16 KB [d][kv], swizzled
  __shared__ unsigned short Pb[2 * 8 * 16 * 64];     // 32 KB: [tile][wave][q16][kv64]

  const int tid  = threadIdx.x;
  const int lane = tid & 63, w = tid >> 6;           // w in 0..7
  const int quad = lane >> 4, lm = lane & 15;
  unsigned short* PbA = Pb + w * 1024;               // wave-private, tile A
  unsigned short* PbB = Pb + 8192 + w * 1024;        // wave-private, tile B

  const int h = blockIdx.x >> 5, pr = blockIdx.x & 31;
  const int pt = pr >> 4, rem = pr & 15;
  const int nth = rem >> 2, ntw = rem & 3;
  const int qtA = pt * 32 + nth * 4 + ntw;           // ntt = 2*pt
  const int qtB = qtA + 16;                          // ntt = 2*pt+1 (same window)
  const int kt0 = pt;                                // verified: both ntt map to pt
  const int kh0 = min(max(nth, 1), 3) - 1;
  const int kw0 = min(max(ntw, 1), 3) - 1;

  // Q B-frags (Q pre-scaled by CSC): n=q = w*16+lm, k=d = kh*32+quad*8+j
  short8 bqA[2], bqB[2];
#pragma unroll
  for (int kh = 0; kh < 2; ++kh) {
    bqA[kh] = *(const short8*)(Q + (size_t)(qtA * 128 + w * 16 + lm) * 1024
                                 + h * 64 + kh * 32 + quad * 8);
    bqB[kh] = *(const short8*)(Q + (size_t)(qtB * 128 + w * 16 + lm) * 1024
                                 + h * 64 + kh * 32 + quad * 8);
  }

  short8 ones8;
#pragma unroll
  for (int j = 0; j < 8; ++j) ones8[j] = (short)0x3F80;   // bf16 1.0

  f32x4 oA[4] = {}, oB[4] = {};                      // [d-tile]
  f32x4 lA = {}, lB = {};                            // row sums of P

  // ---- prologue: stage K tile 0, drain, barrier ----
  {
    const int kvt0 = kt0 * 16 + kh0 * 4 + kw0;
#pragma unroll
    for (int i = 0; i < 2; ++i) {
      int cid = i * 512 + tid;
      int r = cid >> 3, c = cid & 7, cg = c ^ (r & 7);
      int base = (i * 512 + (tid & 448)) * 8;        // wave-uniform LDS dst (u16)
      GLOAD_LDS16(K + (size_t)(kvt0 * 128 + r) * 1024 + h * 64 + cg * 8, Ks + base);
    }
  }
  __syncthreads();                                   // K[0] landed

  for (int it = 0; it < 12; ++it) {
    const int tt2 = it >> 2, hh2 = (it >> 1) & 1, ww2 = it & 1;
    const int kvt = (kt0 + tt2) * 16 + (kh0 + hh2) * 4 + (kw0 + ww2);

    // issue V[it] (latency hidden under 2x QK^T + exp2)
#pragma unroll
    for (int i = 0; i < 2; ++i) {
      int cid = i * 512 + tid;
      int d = cid >> 4, c = cid & 15, cg = c ^ (d & 7);
      int base = (i * 512 + (tid & 448)) * 8;
      GLOAD_LDS16(Vt + (size_t)(h * 64 + d) * 8192 + kvt * 128 + cg * 8, Vs + base);
    }

    // ---- tile A: S^T = K*Q^T, then P = exp2 -> packed registers ----
    u32x2 pkA[8], pkB[8];
    {
      f32x4 sa[8] = {};
#pragma unroll
      for (int kh = 0; kh < 2; ++kh) {
        short8 ak[8];
#pragma unroll
        for (int rt = 0; rt < 8; ++rt)
          ak[rt] = *(const short8*)(Ks + (rt * 16 + lm) * 64 + (((kh * 4 + quad) ^ (lm & 7)) * 8));
        __builtin_amdgcn_s_setprio(1);
#pragma unroll
        for (int rt = 0; rt < 8; ++rt)
          sa[rt] = MFMA_BF16(ak[rt], bqA[kh], sa[rt]);
        __builtin_amdgcn_s_setprio(0);
      }
#pragma unroll
      for (int rt = 0; rt < 8; ++rt) {
        pkA[rt][0] = pack2bf(exp2f(sa[rt][0]), exp2f(sa[rt][1]));
        pkA[rt][1] = pack2bf(exp2f(sa[rt][2]), exp2f(sa[rt][3]));
      }
    }
    // ---- tile B (independent chain; overlaps tile A's exp2) ----
    {
      f32x4 sb[8] = {};
#pragma unroll
      for (int kh = 0; kh < 2; ++kh) {
        short8 ak[8];
#pragma unroll
        for (int rt = 0; rt < 8; ++rt)
          ak[rt] = *(const short8*)(Ks + (rt * 16 + lm) * 64 + (((kh * 4 + quad) ^ (lm & 7)) * 8));
        __builtin_amdgcn_s_setprio(1);
#pragma unroll
        for (int rt = 0; rt < 8; ++rt)
          sb[rt] = MFMA_BF16(ak[rt], bqB[kh], sb[rt]);
        __builtin_amdgcn_s_setprio(0);
      }
#pragma unroll
      for (int rt = 0; rt < 8; ++rt) {
        pkB[rt][0] = pack2bf(exp2f(sb[rt][0]), exp2f(sb[rt][1]));
        pkB[rt][1] = pack2bf(exp2f(sb[rt][2]), exp2f(sb[rt][3]));
      }
    }

    __syncthreads();   // drains vmcnt -> V[it] landed; all waves done reading Ks

    // prefetch K[it+1] into Ks (latency hidden under PV)
    if (it < 11) {
      const int jt = it + 1;
      const int t2 = jt >> 2, h2 = (jt >> 1) & 1, w2 = jt & 1;
      const int kvn = (kt0 + t2) * 16 + (kh0 + h2) * 4 + (kw0 + w2);
#pragma unroll
      for (int i = 0; i < 2; ++i) {
        int cid = i * 512 + tid;
        int r = cid >> 3, c = cid & 7, cg = c ^ (r & 7);
        int base = (i * 512 + (tid & 448)) * 8;
        GLOAD_LDS16(K + (size_t)(kvn * 128 + r) * 1024 + h * 64 + cg * 8, Ks + base);
      }
    }

    // ---- PV for both tiles, shared V-frag reads ----
    // Same-wave LDS ops are processed in order, so half-1 writes cannot pass
    // half-0 reads; PbA/PbB are wave-private so no barrier is needed.
#pragma unroll
    for (int half = 0; half < 2; ++half) {
#pragma unroll
      for (int rt4 = 0; rt4 < 4; ++rt4) {
        // kv-local = rt4*16+quad*4 -> chunk 2rt4+(quad>>1), 8B half quad&1, chunk ^= lm&7
        int off = lm * 64 + (((rt4 * 2 + (quad >> 1)) ^ (lm & 7)) * 8) + (quad & 1) * 4;
        *(u32x2*)(PbA + off) = pkA[half * 4 + rt4];
        *(u32x2*)(PbB + off) = pkB[half * 4 + rt4];
      }
#pragma unroll
      for (int ks2 = 0; ks2 < 2; ++ks2) {
        int aoff = lm * 64 + (((ks2 * 4 + quad) ^ (lm & 7)) * 8);
        short8 apA = *(const short8*)(PbA + aoff);
        short8 apB = *(const short8*)(PbB + aoff);
        __builtin_amdgcn_s_setprio(1);
        lA = MFMA_BF16(apA, ones8, lA);
        lB = MFMA_BF16(apB, ones8, lB);
        __builtin_amdgcn_s_setprio(0);
        const int ks = half * 2 + ks2;
#pragma unroll
        for (int nt = 0; nt < 4; ++nt) {
          short8 bv = *(const short8*)(Vs + (nt * 16 + lm) * 128 + (((ks * 4 + quad) ^ (lm & 7)) * 8));
          __builtin_amdgcn_s_setprio(1);
          oA[nt] = MFMA_BF16(apA, bv, oA[nt]);
          oB[nt] = MFMA_BF16(apB, bv, oB[nt]);
          __builtin_amdgcn_s_setprio(0);
        }
      }
    }

    __syncthreads();   // drains vmcnt -> K[it+1] landed; all waves done reading Vs
  }

  // normalize by l and store (rows q = quad*4+g -> per-lane l)
#pragma unroll
  for (int g = 0; g < 4; ++g) {
    float invA = 1.0f / lA[g];
    float invB = 1.0f / lB[g];
#pragma unroll
    for (int nt = 0; nt < 4; ++nt) {
      int RA = qtA * 128 + w * 16 + quad * 4 + g;
      int RB = qtB * 128 + w * 16 + quad * 4 + g;
      O[(size_t)RA * 1024 + h * 64 + nt * 16 + lm] = f2bf(oA[nt][g] * invA);
      O[(size_t)RB * 1024 + h * 64 + nt * 16 + lm] = f2bf(oB[nt][g] * invB);
    }
  }
}

// ---------- host ----------
extern "C" void kernel_launch(void* const* d_in, const int* in_sizes, int n_in,
                              void* d_out, int out_size, void* d_ws, size_t ws_size,
                              hipStream_t stream) {
  const float* hs = (const float*)d_in[0];
  const float* wq = (const float*)d_in[1];
  const float* wk = (const float*)d_in[2];
  const float* wv = (const float*)d_in[3];
  const float* wo = (const float*)d_in[4];
  float* out = (float*)d_out;                        // reference output dtype = float32

  const size_t NEL = 8388608;                        // 8192*1024
  unsigned short* ws  = (unsigned short*)d_ws;
  unsigned short* HSt = ws;                          // [8192][1024] tile-ordered
  unsigned short* Qb  = ws + 1 * NEL;
  unsigned short* Kb  = ws + 2 * NEL;
  unsigned short* Vb  = ws + 3 * NEL;
  unsigned short* Vtb = ws + 4 * NEL;                // [16][64][8192]
  unsigned short* Ot  = ws + 5 * NEL;
  unsigned short* Wt  = ws + 6 * NEL;                // 4 x [1024][1024] transposed
  if (ws_size < (6 * NEL + 4 * 1048576) * sizeof(unsigned short)) return;

  permute_hs<<<4096, 256, 0, stream>>>(hs, HSt);
  transpose_w<<<dim3(256, 4), 256, 0, stream>>>(wq, wk, wv, wo, Wt);
  gemm_qkv<<<dim3(8, 64, 3), 256, 0, stream>>>(HSt, Wt, Qb);
  transpose_v<<<dim3(64, 16), 256, 0, stream>>>(Vb, Vtb);
  attn<<<512, 512, 0, stream>>>(Qb, Kb, Vtb, Ot);   // 16 heads x 32 q-tile pairs
  gemm_out<<<dim3(8, 64, 1), 256, 0, stream>>>(Ot, Wt + 3 * 1048576, out);
  (void)in_sizes; (void)n_in; (void)out_size;
}

// Round 6
// 283.985 us; speedup vs baseline: 1.6153x; 1.6153x over previous
//
#include <hip/hip_runtime.h>
#include <hip/hip_bf16.h>
#include <math.h>

// ---------- types ----------
typedef __attribute__((ext_vector_type(8))) short          short8;   // 8 bf16 (MFMA frag)
typedef __attribute__((ext_vector_type(8))) unsigned short u16x8;    // 16B chunk
typedef __attribute__((ext_vector_type(2))) unsigned int   u32x2;    // 8B chunk
typedef __attribute__((ext_vector_type(4))) float          f32x4;    // MFMA acc

#define MFMA_BF16(a, b, c) __builtin_amdgcn_mfma_f32_16x16x32_bf16((a), (b), (c), 0, 0, 0)

// async global->LDS, 16B per lane; LDS dst = wave-uniform base + lane*16
#define GLOAD_LDS16(gp, lp)                                        \
  __builtin_amdgcn_global_load_lds(                                \
      (const __attribute__((address_space(1))) void*)(gp),         \
      (__attribute__((address_space(3))) void*)(lp), 16, 0, 0)

// B=1, HID=1024, NH=16, D=64, S=8192, TILE=128, NTILE=64, 12 kv tiles/q tile
// Inputs fp32, output fp32 (verified rounds 1/5).

__device__ __forceinline__ unsigned short f2bf(float f) {
  union { float f; unsigned int u; } v; v.f = f;
  unsigned int r = v.u + 0x7fffu + ((v.u >> 16) & 1u);   // RNE
  return (unsigned short)(r >> 16);
}
// pack two positive floats to a bf16 pair in ONE VALU op (a -> low 16, b -> high).
// T12 recipe: no builtin on gfx950; plain (non-volatile) asm so scheduler can move it.
__device__ __forceinline__ unsigned int pack2bf(float a, float b) {
  unsigned int r;
  asm("v_cvt_pk_bf16_f32 %0, %1, %2" : "=v"(r) : "v"(a), "v"(b));
  return r;
}

// tile-order row r -> natural sequence index s
__device__ __forceinline__ int row_to_seq(int r) {
  int tile = r >> 7, pos = r & 127;
  int ntt = tile >> 4, nth = (tile >> 2) & 3, ntw = tile & 3;
  int tt  = pos >> 6,  th  = (pos >> 3) & 7,  tw  = pos & 7;
  return ((ntt * 2 + tt) << 10) | ((nth * 8 + th) << 5) | (ntw * 8 + tw);
}

// ---------- kernel 1: permute hidden_states rows into tile order (+cast fp32->bf16) ----------
__global__ __launch_bounds__(256) void permute_hs(const float* __restrict__ in,
                                                  unsigned short* __restrict__ out) {
  int cid = blockIdx.x * 256 + threadIdx.x;          // 1,048,576 chunks of 8 elems
  int r = cid >> 7, c = (cid & 127) * 8;
  int s = row_to_seq(r);
  const float* f = in + (size_t)s * 1024 + c;
  u16x8 v;
#pragma unroll
  for (int j = 0; j < 8; ++j) v[j] = f2bf(f[j]);
  *(u16x8*)(out + (size_t)r * 1024 + c) = v;
}

// ---------- kernel 2: transpose the 4 weight matrices [K][N] -> [N][K] (+cast) ----------
__global__ __launch_bounds__(256) void transpose_w(const float* __restrict__ w0,
                                                   const float* __restrict__ w1,
                                                   const float* __restrict__ w2,
                                                   const float* __restrict__ w3,
                                                   unsigned short* __restrict__ out) {
  __shared__ unsigned short Lt[64 * 68];             // [n][k] tile, pad 68
  int m = blockIdx.y;
  const float* W = (m == 0) ? w0 : (m == 1) ? w1 : (m == 2) ? w2 : w3;
  unsigned short* O = out + (size_t)m * 1048576;
  int k0 = (blockIdx.x >> 4) * 64, n0 = (blockIdx.x & 15) * 64;
  int tid = threadIdx.x;
#pragma unroll
  for (int i = 0; i < 2; ++i) {
    int cid = i * 256 + tid;
    int kr = cid >> 3, c = cid & 7;
    const float* f = W + (size_t)(k0 + kr) * 1024 + n0 + c * 8;
#pragma unroll
    for (int j = 0; j < 8; ++j) Lt[(c * 8 + j) * 68 + kr] = f2bf(f[j]);
  }
  __syncthreads();
#pragma unroll
  for (int i = 0; i < 2; ++i) {
    int cid = i * 256 + tid;
    int nr = cid >> 3, c = cid & 7;
    u16x8 v;
#pragma unroll
    for (int j = 0; j < 8; ++j) v[j] = Lt[nr * 68 + c * 8 + j];
    *(u16x8*)(O + (size_t)(n0 + nr) * 1024 + k0 + c * 8) = v;
  }
}

// ---------- gemm_bt: C[M][1024] = (A[M][1024] * Bt[1024][1024]^T) * scale ----------
// 128x128 block tile, BK=64, 4 waves (2x2 of 64x64), XOR-8 swizzled LDS,
// global_load_lds(16B) staging. OUT_F32: final output writes float.
template <int SCATTER, int OUT_F32>
__device__ __forceinline__ void gemm_bt_body(const unsigned short* __restrict__ A,
                                             const unsigned short* __restrict__ Bt,
                                             void* __restrict__ Cv,
                                             int row0, int col0, float scale) {
  __shared__ unsigned short As[128 * 64];
  __shared__ unsigned short Bs[128 * 64];
  const int tid  = threadIdx.x;
  const int lane = tid & 63, w = tid >> 6;
  const int quad = lane >> 4, lm = lane & 15;
  const int wr = (w >> 1) * 64, wc = (w & 1) * 64;
  f32x4 acc[4][4] = {};
  for (int kt = 0; kt < 16; ++kt) {
    const int k0 = kt * 64;
    __syncthreads();
#pragma unroll
    for (int i = 0; i < 4; ++i) {
      int cid = i * 256 + tid;
      int r = cid >> 3, c = cid & 7;
      int cg = c ^ (r & 7);                          // swizzle on SOURCE address
      int base = (i * 256 + (tid & 192)) * 8;        // wave-uniform LDS dst (u16)
      GLOAD_LDS16(A  + (size_t)(row0 + r) * 1024 + k0 + cg * 8, As + base);
      GLOAD_LDS16(Bt + (size_t)(col0 + r) * 1024 + k0 + cg * 8, Bs + base);
    }
    __syncthreads();
#pragma unroll
    for (int kh = 0; kh < 2; ++kh) {
      short8 af[4], bf[4];
#pragma unroll
      for (int t = 0; t < 4; ++t) {
        int ca = (kh * 4 + quad) ^ (lm & 7);
        af[t] = *(const short8*)(As + (wr + t * 16 + lm) * 64 + ca * 8);
        bf[t] = *(const short8*)(Bs + (wc + t * 16 + lm) * 64 + ca * 8);
      }
#pragma unroll
      for (int rt = 0; rt < 4; ++rt)
#pragma unroll
        for (int ct = 0; ct < 4; ++ct)
          acc[rt][ct] = MFMA_BF16(af[rt], bf[ct], acc[rt][ct]);
    }
  }
#pragma unroll
  for (int rt = 0; rt < 4; ++rt)
#pragma unroll
    for (int ct = 0; ct < 4; ++ct)
#pragma unroll
      for (int g = 0; g < 4; ++g) {
        int R  = row0 + wr + rt * 16 + quad * 4 + g;
        int Cc = col0 + wc + ct * 16 + lm;
        int Rs = SCATTER ? row_to_seq(R) : R;
        float vv = acc[rt][ct][g] * scale;
        if (OUT_F32) ((float*)Cv)[(size_t)Rs * 1024 + Cc] = vv;
        else ((unsigned short*)Cv)[(size_t)Rs * 1024 + Cc] = f2bf(vv);
      }
}

__global__ __launch_bounds__(256) void gemm_qkv(const unsigned short* __restrict__ A,
                                                const unsigned short* __restrict__ Wt,
                                                unsigned short* __restrict__ QKV) {
  // fold softmax scale (1/8)*log2(e) into Q so attn's exp2 needs no multiply
  float scale = (blockIdx.z == 0) ? 0.18033688011112042f : 1.0f;
  gemm_bt_body<0, 0>(A, Wt + (size_t)blockIdx.z * 1048576,
                     QKV + (size_t)blockIdx.z * 8388608,
                     blockIdx.y * 128, blockIdx.x * 128, scale);
}

__global__ __launch_bounds__(256) void gemm_out(const unsigned short* __restrict__ A,
                                                const unsigned short* __restrict__ Wt,
                                                float* __restrict__ Cout) {
  gemm_bt_body<1, 1>(A, Wt, Cout, blockIdx.y * 128, blockIdx.x * 128, 1.0f);
}

// ---------- kernel: V [8192][16*64] (tile rows) -> Vt [16][64][8192] ----------
__global__ __launch_bounds__(256) void transpose_v(const unsigned short* __restrict__ V,
                                                   unsigned short* __restrict__ Vt) {
  __shared__ unsigned short Lt[64 * 136];            // [d][r] tile, pad 136
  int kt = blockIdx.x, h = blockIdx.y, tid = threadIdx.x;
#pragma unroll
  for (int i = 0; i < 4; ++i) {
    int cid = i * 256 + tid;                         // 1024 chunks
    int r = cid >> 3, c = cid & 7;
    u16x8 v = *(const u16x8*)(V + (size_t)(kt * 128 + r) * 1024 + h * 64 + c * 8);
#pragma unroll
    for (int j = 0; j < 8; ++j) Lt[(c * 8 + j) * 136 + r] = v[j];
  }
  __syncthreads();
#pragma unroll
  for (int i = 0; i < 4; ++i) {
    int cid = i * 256 + tid;
    int d = cid >> 4, c = cid & 15;
    u16x8 v = *(const u16x8*)(Lt + d * 136 + c * 8);
    *(u16x8*)(Vt + (size_t)(h * 64 + d) * 8192 + kt * 128 + c * 8) = v;
  }
}

// ---------- attention: one block per (head, q-tile), 512 threads (8 waves) ----------
// Round-2 structure (best measured: 104 us) + VALU trim:
//  * staging addresses precomputed as per-lane u32 element offsets; per-iter
//    address = offset + (kvt<<17) for K, + (kvt<<7) for V (saddr-form loads)
//  * P pack via single v_cvt_pk_bf16_f32 (was 3 ops/pair)
//  * s_setprio(1) around MFMA bursts (m191: helps attn-style phase-diverse waves)
// Pipelined staging: V[it] issued at iteration top (drained by mid barrier,
// hidden under QK^T+exp2); K[it+1] issued right after the mid barrier
// (drained by end barrier, hidden under PV). 2 barriers/iter.
// Pb: per-wave 2 KB [q16][kv64] slice, two kv-halves per iteration (round-2
// layout; quartering doubled bank conflicts in round 4).
// LDS: Ks 16 + Vs 16 + Pb 16 = 48 KB. (512,4): round 3/5 lesson — the
// allocator settles at <=64 VGPR here; structures needing more spill 10x.
__global__ __launch_bounds__(512, 4) void attn(const unsigned short* __restrict__ Q,
                                               const unsigned short* __restrict__ K,
                                               const unsigned short* __restrict__ Vt,
                                               unsigned short* __restrict__ O) {
  __shared__ unsigned short Ks[128 * 64];            // 16 KB [kv][d], swizzled
  __shared__ unsigned short Vs[64 * 128];            // 16 KB [d][kv], swizzled
  __shared__ unsigned short Pb[8 * 16 * 64];         // 16 KB: per-wave 2 KB P slice

  const int tid  = threadIdx.x;
  const int lane = tid & 63, w = tid >> 6;           // w in 0..7
  const int quad = lane >> 4, lm = lane & 15;
  unsigned short* Pbw = Pb + w * 1024;               // wave-private [q 16][kv 64]

  const int h = blockIdx.x >> 6, qt = blockIdx.x & 63;
  const int ntt = qt >> 4, nth = (qt >> 2) & 3, ntw = qt & 3;
  const int kt0 = min(max(ntt, 1), 2) - 1;           // t-window start tile
  const int kh0 = min(max(nth, 1), 3) - 1;
  const int kw0 = min(max(ntw, 1), 3) - 1;

  // per-lane invariant staging offsets (u32 element offsets; +4 VGPR, -24 VALU/iter)
  const int cid1 = 512 + tid;
  const int rK0 = tid  >> 3, cgK0 = (tid  & 7) ^ (rK0 & 7);
  const int rK1 = cid1 >> 3, cgK1 = (cid1 & 7) ^ (rK1 & 7);
  const unsigned koff0 = rK0 * 1024 + h * 64 + cgK0 * 8;
  const unsigned koff1 = rK1 * 1024 + h * 64 + cgK1 * 8;
  const int dV0 = tid  >> 4, cgV0 = (tid  & 15) ^ (dV0 & 7);
  const int dV1 = cid1 >> 4, cgV1 = (cid1 & 15) ^ (dV1 & 7);
  const unsigned voff0 = (h * 64 + dV0) * 8192 + cgV0 * 8;
  const unsigned voff1 = (h * 64 + dV1) * 8192 + cgV1 * 8;
  const unsigned ldsD0 = (tid & 448) * 8;            // wave-uniform LDS dst (u16)
  const unsigned ldsD1 = (512 + (tid & 448)) * 8;

  // Q B-frags (Q pre-scaled by CSC): n=q = w*16+lm, k=d = kh*32+quad*8+j
  short8 bq[2];
#pragma unroll
  for (int kh = 0; kh < 2; ++kh)
    bq[kh] = *(const short8*)(Q + (size_t)(qt * 128 + w * 16 + lm) * 1024
                                + h * 64 + kh * 32 + quad * 8);

  short8 ones8;
#pragma unroll
  for (int j = 0; j < 8; ++j) ones8[j] = (short)0x3F80;   // bf16 1.0

  f32x4 o_acc[4] = {};                               // [d-tile]
  f32x4 l_acc = {};                                  // row sums of P

  // ---- prologue: stage K tile 0, drain, barrier ----
  {
    const unsigned k0 = (unsigned)(kt0 * 16 + kh0 * 4 + kw0) << 17;
    GLOAD_LDS16(K + koff0 + k0, Ks + ldsD0);
    GLOAD_LDS16(K + koff1 + k0, Ks + ldsD1);
  }
  __syncthreads();                                   // K[0] landed

  for (int it = 0; it < 12; ++it) {
    const int tt2 = it >> 2, hh2 = (it >> 1) & 1, ww2 = it & 1;
    const int kvt = (kt0 + tt2) * 16 + (kh0 + hh2) * 4 + (kw0 + ww2);

    // issue V[it] (latency hidden under QK^T + exp2); Vs reads of the previous
    // iteration completed before the end-of-loop barrier.
    {
      const unsigned v0 = (unsigned)kvt << 7;
      GLOAD_LDS16(Vt + voff0 + v0, Vs + ldsD0);
      GLOAD_LDS16(Vt + voff1 + v0, Vs + ldsD1);
    }

    // S^T[kv 128][q 16(wave)] = K * Q^T
    f32x4 sa[8] = {};                                // [kv-tile rt]
#pragma unroll
    for (int kh = 0; kh < 2; ++kh) {
      short8 ak[8];
#pragma unroll
      for (int rt = 0; rt < 8; ++rt)
        ak[rt] = *(const short8*)(Ks + (rt * 16 + lm) * 64 + (((kh * 4 + quad) ^ (lm & 7)) * 8));
      __builtin_amdgcn_s_setprio(1);
#pragma unroll
      for (int rt = 0; rt < 8; ++rt)
        sa[rt] = MFMA_BF16(ak[rt], bq[kh], sa[rt]);
      __builtin_amdgcn_s_setprio(0);
    }

    // P = exp2(S^T) packed to bf16 pairs, kept in registers across the barrier
    u32x2 pk[8];
#pragma unroll
    for (int rt = 0; rt < 8; ++rt) {
      pk[rt][0] = pack2bf(exp2f(sa[rt][0]), exp2f(sa[rt][1]));
      pk[rt][1] = pack2bf(exp2f(sa[rt][2]), exp2f(sa[rt][3]));
    }

    __syncthreads();   // drains vmcnt -> V[it] landed; all waves done reading Ks

    // prefetch K[it+1] into Ks (latency hidden under PV)
    if (it < 11) {
      const int jt = it + 1;
      const int t2 = jt >> 2, h2 = (jt >> 1) & 1, w2 = jt & 1;
      const unsigned kn = (unsigned)((kt0 + t2) * 16 + (kh0 + h2) * 4 + (kw0 + w2)) << 17;
      GLOAD_LDS16(K + koff0 + kn, Ks + ldsD0);
      GLOAD_LDS16(K + koff1 + kn, Ks + ldsD1);
    }

    // O += P * V ; l += P * 1  — two kv-halves through the 2 KB Pb slice.
    // Same-wave LDS ops are processed in order, so half-1 writes cannot pass
    // half-0 reads; Pbw is wave-private so no barrier is needed.
#pragma unroll
    for (int half = 0; half < 2; ++half) {
#pragma unroll
      for (int rt4 = 0; rt4 < 4; ++rt4) {
        // kv offset rt4*16+quad*4 -> chunk 2rt4+(quad>>1), 8B half quad&1, chunk ^= lm&7
        *(u32x2*)(Pbw + lm * 64 + (((rt4 * 2 + (quad >> 1)) ^ (lm & 7)) * 8) + (quad & 1) * 4)
            = pk[half * 4 + rt4];
      }
#pragma unroll
      for (int ks2 = 0; ks2 < 2; ++ks2) {
        short8 ap = *(const short8*)(Pbw + lm * 64 + (((ks2 * 4 + quad) ^ (lm & 7)) * 8));
        const int ks = half * 2 + ks2;
        __builtin_amdgcn_s_setprio(1);
        l_acc = MFMA_BF16(ap, ones8, l_acc);
        __builtin_amdgcn_s_setprio(0);
#pragma unroll
        for (int nt = 0; nt < 4; ++nt) {
          short8 bv = *(const short8*)(Vs + (nt * 16 + lm) * 128 + (((ks * 4 + quad) ^ (lm & 7)) * 8));
          __builtin_amdgcn_s_setprio(1);
          o_acc[nt] = MFMA_BF16(ap, bv, o_acc[nt]);
          __builtin_amdgcn_s_setprio(0);
        }
      }
    }

    __syncthreads();   // drains vmcnt -> K[it+1] landed; all waves done reading Vs
  }

  // normalize by l and store (rows q = quad*4+g -> per-lane l)
#pragma unroll
  for (int g = 0; g < 4; ++g) {
    float inv = 1.0f / l_acc[g];
#pragma unroll
    for (int nt = 0; nt < 4; ++nt) {
      int R = qt * 128 + w * 16 + quad * 4 + g;
      O[(size_t)R * 1024 + h * 64 + nt * 16 + lm] = f2bf(o_acc[nt][g] * inv);
    }
  }
}

// ---------- host ----------
extern "C" void kernel_launch(void* const* d_in, const int* in_sizes, int n_in,
                              void* d_out, int out_size, void* d_ws, size_t ws_size,
                              hipStream_t stream) {
  const float* hs = (const float*)d_in[0];
  const float* wq = (const float*)d_in[1];
  const float* wk = (const float*)d_in[2];
  const float* wv = (const float*)d_in[3];
  const float* wo = (const float*)d_in[4];
  float* out = (float*)d_out;                        // reference output dtype = float32

  const size_t NEL = 8388608;                        // 8192*1024
  unsigned short* ws  = (unsigned short*)d_ws;
  unsigned short* HSt = ws;                          // [8192][1024] tile-ordered
  unsigned short* Qb  = ws + 1 * NEL;
  unsigned short* Kb  = ws + 2 * NEL;
  unsigned short* Vb  = ws + 3 * NEL;
  unsigned short* Vtb = ws + 4 * NEL;                // [16][64][8192]
  unsigned short* Ot  = ws + 5 * NEL;
  unsigned short* Wt  = ws + 6 * NEL;                // 4 x [1024][1024] transposed
  if (ws_size < (6 * NEL + 4 * 1048576) * sizeof(unsigned short)) return;

  permute_hs<<<4096, 256, 0, stream>>>(hs, HSt);
  transpose_w<<<dim3(256, 4), 256, 0, stream>>>(wq, wk, wv, wo, Wt);
  gemm_qkv<<<dim3(8, 64, 3), 256, 0, stream>>>(HSt, Wt, Qb);
  transpose_v<<<dim3(64, 16), 256, 0, stream>>>(Vb, Vtb);
  attn<<<1024, 512, 0, stream>>>(Qb, Kb, Vtb, Ot);
  gemm_out<<<dim3(8, 64, 1), 256, 0, stream>>>(Ot, Wt + 3 * 1048576, out);
  (void)in_sizes; (void)n_in; (void)out_size;
}

// Round 7
// 283.239 us; speedup vs baseline: 1.6195x; 1.0026x over previous
//
#include <hip/hip_runtime.h>
#include <hip/hip_bf16.h>
#include <math.h>

// ---------- types ----------
typedef __attribute__((ext_vector_type(8))) short          short8;   // 8 bf16 (MFMA frag)
typedef __attribute__((ext_vector_type(8))) unsigned short u16x8;    // 16B chunk
typedef __attribute__((ext_vector_type(2))) unsigned int   u32x2;    // 8B chunk
typedef __attribute__((ext_vector_type(4))) float          f32x4;    // MFMA acc

#define MFMA_BF16(a, b, c) __builtin_amdgcn_mfma_f32_16x16x32_bf16((a), (b), (c), 0, 0, 0)

// async global->LDS, 16B per lane; LDS dst = wave-uniform base + lane*16
#define GLOAD_LDS16(gp, lp)                                        \
  __builtin_amdgcn_global_load_lds(                                \
      (const __attribute__((address_space(1))) void*)(gp),         \
      (__attribute__((address_space(3))) void*)(lp), 16, 0, 0)

// B=1, HID=1024, NH=16, D=64, S=8192, TILE=128, NTILE=64, 12 kv tiles/q tile
// Inputs fp32, output fp32 (verified rounds 1/5).

__device__ __forceinline__ unsigned short f2bf(float f) {
  union { float f; unsigned int u; } v; v.f = f;
  unsigned int r = v.u + 0x7fffu + ((v.u >> 16) & 1u);   // RNE
  return (unsigned short)(r >> 16);
}
// pack two positive floats to a bf16 pair in ONE VALU op (a -> low 16, b -> high).
// T12 recipe: no builtin on gfx950; plain (non-volatile) asm so scheduler can move it.
__device__ __forceinline__ unsigned int pack2bf(float a, float b) {
  unsigned int r;
  asm("v_cvt_pk_bf16_f32 %0, %1, %2" : "=v"(r) : "v"(a), "v"(b));
  return r;
}

// tile-order row r -> natural sequence index s
__device__ __forceinline__ int row_to_seq(int r) {
  int tile = r >> 7, pos = r & 127;
  int ntt = tile >> 4, nth = (tile >> 2) & 3, ntw = tile & 3;
  int tt  = pos >> 6,  th  = (pos >> 3) & 7,  tw  = pos & 7;
  return ((ntt * 2 + tt) << 10) | ((nth * 8 + th) << 5) | (ntw * 8 + tw);
}

// ---------- kernel 1: permute hidden_states rows into tile order (+cast fp32->bf16) ----------
__global__ __launch_bounds__(256) void permute_hs(const float* __restrict__ in,
                                                  unsigned short* __restrict__ out) {
  int cid = blockIdx.x * 256 + threadIdx.x;          // 1,048,576 chunks of 8 elems
  int r = cid >> 7, c = (cid & 127) * 8;
  int s = row_to_seq(r);
  const float* f = in + (size_t)s * 1024 + c;
  u16x8 v;
#pragma unroll
  for (int j = 0; j < 8; ++j) v[j] = f2bf(f[j]);
  *(u16x8*)(out + (size_t)r * 1024 + c) = v;
}

// ---------- kernel 2: transpose the 4 weight matrices [K][N] -> [N][K] (+cast) ----------
__global__ __launch_bounds__(256) void transpose_w(const float* __restrict__ w0,
                                                   const float* __restrict__ w1,
                                                   const float* __restrict__ w2,
                                                   const float* __restrict__ w3,
                                                   unsigned short* __restrict__ out) {
  __shared__ unsigned short Lt[64 * 68];             // [n][k] tile, pad 68
  int m = blockIdx.y;
  const float* W = (m == 0) ? w0 : (m == 1) ? w1 : (m == 2) ? w2 : w3;
  unsigned short* O = out + (size_t)m * 1048576;
  int k0 = (blockIdx.x >> 4) * 64, n0 = (blockIdx.x & 15) * 64;
  int tid = threadIdx.x;
#pragma unroll
  for (int i = 0; i < 2; ++i) {
    int cid = i * 256 + tid;
    int kr = cid >> 3, c = cid & 7;
    const float* f = W + (size_t)(k0 + kr) * 1024 + n0 + c * 8;
#pragma unroll
    for (int j = 0; j < 8; ++j) Lt[(c * 8 + j) * 68 + kr] = f2bf(f[j]);
  }
  __syncthreads();
#pragma unroll
  for (int i = 0; i < 2; ++i) {
    int cid = i * 256 + tid;
    int nr = cid >> 3, c = cid & 7;
    u16x8 v;
#pragma unroll
    for (int j = 0; j < 8; ++j) v[j] = Lt[nr * 68 + c * 8 + j];
    *(u16x8*)(O + (size_t)(n0 + nr) * 1024 + k0 + c * 8) = v;
  }
}

// ---------- gemm_bt: C[M][1024] = (A[M][1024] * Bt[1024][1024]^T) * scale ----------
// 128x128 block tile, BK=64, 4 waves (2x2 of 64x64), XOR-8 swizzled LDS,
// global_load_lds(16B) staging. OUT_F32: final output writes float.
template <int SCATTER, int OUT_F32>
__device__ __forceinline__ void gemm_bt_body(const unsigned short* __restrict__ A,
                                             const unsigned short* __restrict__ Bt,
                                             void* __restrict__ Cv,
                                             int row0, int col0, float scale) {
  __shared__ unsigned short As[128 * 64];
  __shared__ unsigned short Bs[128 * 64];
  const int tid  = threadIdx.x;
  const int lane = tid & 63, w = tid >> 6;
  const int quad = lane >> 4, lm = lane & 15;
  const int wr = (w >> 1) * 64, wc = (w & 1) * 64;
  f32x4 acc[4][4] = {};
  for (int kt = 0; kt < 16; ++kt) {
    const int k0 = kt * 64;
    __syncthreads();
#pragma unroll
    for (int i = 0; i < 4; ++i) {
      int cid = i * 256 + tid;
      int r = cid >> 3, c = cid & 7;
      int cg = c ^ (r & 7);                          // swizzle on SOURCE address
      int base = (i * 256 + (tid & 192)) * 8;        // wave-uniform LDS dst (u16)
      GLOAD_LDS16(A  + (size_t)(row0 + r) * 1024 + k0 + cg * 8, As + base);
      GLOAD_LDS16(Bt + (size_t)(col0 + r) * 1024 + k0 + cg * 8, Bs + base);
    }
    __syncthreads();
#pragma unroll
    for (int kh = 0; kh < 2; ++kh) {
      short8 af[4], bf[4];
#pragma unroll
      for (int t = 0; t < 4; ++t) {
        int ca = (kh * 4 + quad) ^ (lm & 7);
        af[t] = *(const short8*)(As + (wr + t * 16 + lm) * 64 + ca * 8);
        bf[t] = *(const short8*)(Bs + (wc + t * 16 + lm) * 64 + ca * 8);
      }
#pragma unroll
      for (int rt = 0; rt < 4; ++rt)
#pragma unroll
        for (int ct = 0; ct < 4; ++ct)
          acc[rt][ct] = MFMA_BF16(af[rt], bf[ct], acc[rt][ct]);
    }
  }
#pragma unroll
  for (int rt = 0; rt < 4; ++rt)
#pragma unroll
    for (int ct = 0; ct < 4; ++ct)
#pragma unroll
      for (int g = 0; g < 4; ++g) {
        int R  = row0 + wr + rt * 16 + quad * 4 + g;
        int Cc = col0 + wc + ct * 16 + lm;
        int Rs = SCATTER ? row_to_seq(R) : R;
        float vv = acc[rt][ct][g] * scale;
        if (OUT_F32) ((float*)Cv)[(size_t)Rs * 1024 + Cc] = vv;
        else ((unsigned short*)Cv)[(size_t)Rs * 1024 + Cc] = f2bf(vv);
      }
}

__global__ __launch_bounds__(256) void gemm_qkv(const unsigned short* __restrict__ A,
                                                const unsigned short* __restrict__ Wt,
                                                unsigned short* __restrict__ QKV) {
  // fold softmax scale (1/8)*log2(e) into Q so attn's exp2 needs no multiply
  float scale = (blockIdx.z == 0) ? 0.18033688011112042f : 1.0f;
  gemm_bt_body<0, 0>(A, Wt + (size_t)blockIdx.z * 1048576,
                     QKV + (size_t)blockIdx.z * 8388608,
                     blockIdx.y * 128, blockIdx.x * 128, scale);
}

__global__ __launch_bounds__(256) void gemm_out(const unsigned short* __restrict__ A,
                                                const unsigned short* __restrict__ Wt,
                                                float* __restrict__ Cout) {
  gemm_bt_body<1, 1>(A, Wt, Cout, blockIdx.y * 128, blockIdx.x * 128, 1.0f);
}

// ---------- kernel: V [8192][16*64] (tile rows) -> Vt [16][64][8192] ----------
__global__ __launch_bounds__(256) void transpose_v(const unsigned short* __restrict__ V,
                                                   unsigned short* __restrict__ Vt) {
  __shared__ unsigned short Lt[64 * 136];            // [d][r] tile, pad 136
  int kt = blockIdx.x, h = blockIdx.y, tid = threadIdx.x;
#pragma unroll
  for (int i = 0; i < 4; ++i) {
    int cid = i * 256 + tid;                         // 1024 chunks
    int r = cid >> 3, c = cid & 7;
    u16x8 v = *(const u16x8*)(V + (size_t)(kt * 128 + r) * 1024 + h * 64 + c * 8);
#pragma unroll
    for (int j = 0; j < 8; ++j) Lt[(c * 8 + j) * 136 + r] = v[j];
  }
  __syncthreads();
#pragma unroll
  for (int i = 0; i < 4; ++i) {
    int cid = i * 256 + tid;
    int d = cid >> 4, c = cid & 15;
    u16x8 v = *(const u16x8*)(Lt + d * 136 + c * 8);
    *(u16x8*)(Vt + (size_t)(h * 64 + d) * 8192 + kt * 128 + c * 8) = v;
  }
}

// ---------- attention: one block per (head, q-tile), 512 threads (8 waves) ----------
// Round-7: DOUBLE-BUFFERED K and V -> ONE barrier per kv iteration (was 2).
// Per iter: issue K[it+1],V[it+1] into buf[1-p] at the TOP (loads in flight
// across the whole QK^T+exp2+PV phase), compute from buf[p], one end barrier
// that (a) drains vmcnt so buf[1-p] is ready and (b) licenses overwriting
// buf[p] next iter. Barriers/block 24 -> 13.
// VALU trim from round 6 kept: precomputed per-lane staging offsets
// (addr = offset + kvt<<17 / kvt<<7), single-op v_cvt_pk_bf16_f32 P-pack.
// Pb: per-wave 2 KB [q16][kv64], two kv-halves (round-2 layout; quartering
// doubled conflicts in round 4). LDS: Ks 32 + Vs 32 + Pb 16 = 80 KB -> exactly
// 2 blocks/CU; grid 1024 = 4 even rounds, no ragged tail.
// (512,4): rounds 3/5 lesson — allocator settles at <=64 VGPR here; structures
// whose live set exceeds that spill 10x. This one matches round 6's live set.
__global__ __launch_bounds__(512, 4) void attn(const unsigned short* __restrict__ Q,
                                               const unsigned short* __restrict__ K,
                                               const unsigned short* __restrict__ Vt,
                                               unsigned short* __restrict__ O) {
  __shared__ unsigned short Ks[2][128 * 64];         // 32 KB [kv][d], swizzled
  __shared__ unsigned short Vs[2][64 * 128];         // 32 KB [d][kv], swizzled
  __shared__ unsigned short Pb[8 * 16 * 64];         // 16 KB: per-wave 2 KB P slice

  const int tid  = threadIdx.x;
  const int lane = tid & 63, w = tid >> 6;           // w in 0..7
  const int quad = lane >> 4, lm = lane & 15;
  unsigned short* Pbw = Pb + w * 1024;               // wave-private [q 16][kv 64]

  const int h = blockIdx.x >> 6, qt = blockIdx.x & 63;
  const int ntt = qt >> 4, nth = (qt >> 2) & 3, ntw = qt & 3;
  const int kt0 = min(max(ntt, 1), 2) - 1;           // t-window start tile
  const int kh0 = min(max(nth, 1), 3) - 1;
  const int kw0 = min(max(ntw, 1), 3) - 1;

  // per-lane invariant staging offsets (u32 element offsets)
  const int cid1 = 512 + tid;
  const int rK0 = tid  >> 3, cgK0 = (tid  & 7) ^ (rK0 & 7);
  const int rK1 = cid1 >> 3, cgK1 = (cid1 & 7) ^ (rK1 & 7);
  const unsigned koff0 = rK0 * 1024 + h * 64 + cgK0 * 8;
  const unsigned koff1 = rK1 * 1024 + h * 64 + cgK1 * 8;
  const int dV0 = tid  >> 4, cgV0 = (tid  & 15) ^ (dV0 & 7);
  const int dV1 = cid1 >> 4, cgV1 = (cid1 & 15) ^ (dV1 & 7);
  const unsigned voff0 = (h * 64 + dV0) * 8192 + cgV0 * 8;
  const unsigned voff1 = (h * 64 + dV1) * 8192 + cgV1 * 8;
  const unsigned ldsD0 = (tid & 448) * 8;            // wave-uniform LDS dst (u16)
  const unsigned ldsD1 = (512 + (tid & 448)) * 8;

  // Q B-frags (Q pre-scaled by CSC): n=q = w*16+lm, k=d = kh*32+quad*8+j
  short8 bq[2];
#pragma unroll
  for (int kh = 0; kh < 2; ++kh)
    bq[kh] = *(const short8*)(Q + (size_t)(qt * 128 + w * 16 + lm) * 1024
                                + h * 64 + kh * 32 + quad * 8);

  short8 ones8;
#pragma unroll
  for (int j = 0; j < 8; ++j) ones8[j] = (short)0x3F80;   // bf16 1.0

  f32x4 o_acc[4] = {};                               // [d-tile]
  f32x4 l_acc = {};                                  // row sums of P

  // ---- prologue: stage K[0], V[0] into buf 0, drain, barrier ----
  {
    const int kvt0 = kt0 * 16 + kh0 * 4 + kw0;
    const unsigned k0 = (unsigned)kvt0 << 17;
    const unsigned v0 = (unsigned)kvt0 << 7;
    GLOAD_LDS16(K  + koff0 + k0, Ks[0] + ldsD0);
    GLOAD_LDS16(K  + koff1 + k0, Ks[0] + ldsD1);
    GLOAD_LDS16(Vt + voff0 + v0, Vs[0] + ldsD0);
    GLOAD_LDS16(Vt + voff1 + v0, Vs[0] + ldsD1);
  }
  __syncthreads();                                   // K[0],V[0] landed

  for (int it = 0; it < 12; ++it) {
    const int p = it & 1;
    const unsigned short* Ksp = Ks[p];
    const unsigned short* Vsp = Vs[p];

    // issue K[it+1],V[it+1] into buf[1-p]; in flight across this whole iter.
    // buf[1-p] reads finished at the END of iter it-1 (last barrier).
    if (it < 11) {
      const int jt = it + 1;
      const int t2 = jt >> 2, h2 = (jt >> 1) & 1, w2 = jt & 1;
      const int kvn = (kt0 + t2) * 16 + (kh0 + h2) * 4 + (kw0 + w2);
      const unsigned kn = (unsigned)kvn << 17;
      const unsigned vn = (unsigned)kvn << 7;
      GLOAD_LDS16(K  + koff0 + kn, Ks[1 - p] + ldsD0);
      GLOAD_LDS16(K  + koff1 + kn, Ks[1 - p] + ldsD1);
      GLOAD_LDS16(Vt + voff0 + vn, Vs[1 - p] + ldsD0);
      GLOAD_LDS16(Vt + voff1 + vn, Vs[1 - p] + ldsD1);
    }

    // S^T[kv 128][q 16(wave)] = K * Q^T
    f32x4 sa[8] = {};                                // [kv-tile rt]
#pragma unroll
    for (int kh = 0; kh < 2; ++kh) {
      short8 ak[8];
#pragma unroll
      for (int rt = 0; rt < 8; ++rt)
        ak[rt] = *(const short8*)(Ksp + (rt * 16 + lm) * 64 + (((kh * 4 + quad) ^ (lm & 7)) * 8));
      __builtin_amdgcn_s_setprio(1);
#pragma unroll
      for (int rt = 0; rt < 8; ++rt)
        sa[rt] = MFMA_BF16(ak[rt], bq[kh], sa[rt]);
      __builtin_amdgcn_s_setprio(0);
    }

    // P = exp2(S^T) packed to bf16 pairs (registers)
    u32x2 pk[8];
#pragma unroll
    for (int rt = 0; rt < 8; ++rt) {
      pk[rt][0] = pack2bf(exp2f(sa[rt][0]), exp2f(sa[rt][1]));
      pk[rt][1] = pack2bf(exp2f(sa[rt][2]), exp2f(sa[rt][3]));
    }

    // O += P * V ; l += P * 1  — two kv-halves through the 2 KB Pb slice.
    // Same-wave LDS ops are processed in order, so half-1 writes cannot pass
    // half-0 reads; Pbw is wave-private so no barrier is needed.
#pragma unroll
    for (int half = 0; half < 2; ++half) {
#pragma unroll
      for (int rt4 = 0; rt4 < 4; ++rt4) {
        // kv offset rt4*16+quad*4 -> chunk 2rt4+(quad>>1), 8B half quad&1, chunk ^= lm&7
        *(u32x2*)(Pbw + lm * 64 + (((rt4 * 2 + (quad >> 1)) ^ (lm & 7)) * 8) + (quad & 1) * 4)
            = pk[half * 4 + rt4];
      }
#pragma unroll
      for (int ks2 = 0; ks2 < 2; ++ks2) {
        short8 ap = *(const short8*)(Pbw + lm * 64 + (((ks2 * 4 + quad) ^ (lm & 7)) * 8));
        const int ks = half * 2 + ks2;
        short8 bv[4];
#pragma unroll
        for (int nt = 0; nt < 4; ++nt)
          bv[nt] = *(const short8*)(Vsp + (nt * 16 + lm) * 128 + (((ks * 4 + quad) ^ (lm & 7)) * 8));
        __builtin_amdgcn_s_setprio(1);
        l_acc = MFMA_BF16(ap, ones8, l_acc);
#pragma unroll
        for (int nt = 0; nt < 4; ++nt)
          o_acc[nt] = MFMA_BF16(ap, bv[nt], o_acc[nt]);
        __builtin_amdgcn_s_setprio(0);
      }
    }

    // ONE barrier: drains vmcnt (buf[1-p] staged) and licenses overwriting
    // buf[p] at iter it+1.
    __syncthreads();
  }

  // normalize by l and store (rows q = quad*4+g -> per-lane l)
#pragma unroll
  for (int g = 0; g < 4; ++g) {
    float inv = 1.0f / l_acc[g];
#pragma unroll
    for (int nt = 0; nt < 4; ++nt) {
      int R = qt * 128 + w * 16 + quad * 4 + g;
      O[(size_t)R * 1024 + h * 64 + nt * 16 + lm] = f2bf(o_acc[nt][g] * inv);
    }
  }
}

// ---------- host ----------
extern "C" void kernel_launch(void* const* d_in, const int* in_sizes, int n_in,
                              void* d_out, int out_size, void* d_ws, size_t ws_size,
                              hipStream_t stream) {
  const float* hs = (const float*)d_in[0];
  const float* wq = (const float*)d_in[1];
  const float* wk = (const float*)d_in[2];
  const float* wv = (const float*)d_in[3];
  const float* wo = (const float*)d_in[4];
  float* out = (float*)d_out;                        // reference output dtype = float32

  const size_t NEL = 8388608;                        // 8192*1024
  unsigned short* ws  = (unsigned short*)d_ws;
  unsigned short* HSt = ws;                          // [8192][1024] tile-ordered
  unsigned short* Qb  = ws + 1 * NEL;
  unsigned short* Kb  = ws + 2 * NEL;
  unsigned short* Vb  = ws + 3 * NEL;
  unsigned short* Vtb = ws + 4 * NEL;                // [16][64][8192]
  unsigned short* Ot  = ws + 5 * NEL;
  unsigned short* Wt  = ws + 6 * NEL;                // 4 x [1024][1024] transposed
  if (ws_size < (6 * NEL + 4 * 1048576) * sizeof(unsigned short)) return;

  permute_hs<<<4096, 256, 0, stream>>>(hs, HSt);
  transpose_w<<<dim3(256, 4), 256, 0, stream>>>(wq, wk, wv, wo, Wt);
  gemm_qkv<<<dim3(8, 64, 3), 256, 0, stream>>>(HSt, Wt, Qb);
  transpose_v<<<dim3(64, 16), 256, 0, stream>>>(Vb, Vtb);
  attn<<<1024, 512, 0, stream>>>(Qb, Kb, Vtb, Ot);
  gemm_out<<<dim3(8, 64, 1), 256, 0, stream>>>(Ot, Wt + 3 * 1048576, out);
  (void)in_sizes; (void)n_in; (void)out_size;
}

// Round 8
// 280.231 us; speedup vs baseline: 1.6369x; 1.0107x over previous
//
#include <hip/hip_runtime.h>
#include <hip/hip_bf16.h>
#include <math.h>

// ---------- types ----------
typedef __attribute__((ext_vector_type(8))) short          short8;   // 8 bf16 (MFMA frag)
typedef __attribute__((ext_vector_type(8))) unsigned short u16x8;    // 16B chunk
typedef __attribute__((ext_vector_type(2))) unsigned int   u32x2;    // 8B chunk
typedef __attribute__((ext_vector_type(4))) float          f32x4;    // MFMA acc

#define MFMA_BF16(a, b, c) __builtin_amdgcn_mfma_f32_16x16x32_bf16((a), (b), (c), 0, 0, 0)

// async global->LDS, 16B per lane; LDS dst = wave-uniform base + lane*16
#define GLOAD_LDS16(gp, lp)                                        \
  __builtin_amdgcn_global_load_lds(                                \
      (const __attribute__((address_space(1))) void*)(gp),         \
      (__attribute__((address_space(3))) void*)(lp), 16, 0, 0)

// B=1, HID=1024, NH=16, D=64, S=8192, TILE=128, NTILE=64, 12 kv tiles/q tile
// Inputs fp32, output fp32 (verified rounds 1/5).

__device__ __forceinline__ unsigned short f2bf(float f) {
  union { float f; unsigned int u; } v; v.f = f;
  unsigned int r = v.u + 0x7fffu + ((v.u >> 16) & 1u);   // RNE
  return (unsigned short)(r >> 16);
}
// pack two positive floats to a bf16 pair in ONE VALU op (a -> low 16, b -> high).
// T12 recipe: no builtin on gfx950; plain (non-volatile) asm so scheduler can move it.
__device__ __forceinline__ unsigned int pack2bf(float a, float b) {
  unsigned int r;
  asm("v_cvt_pk_bf16_f32 %0, %1, %2" : "=v"(r) : "v"(a), "v"(b));
  return r;
}

// tile-order row r -> natural sequence index s
__device__ __forceinline__ int row_to_seq(int r) {
  int tile = r >> 7, pos = r & 127;
  int ntt = tile >> 4, nth = (tile >> 2) & 3, ntw = tile & 3;
  int tt  = pos >> 6,  th  = (pos >> 3) & 7,  tw  = pos & 7;
  return ((ntt * 2 + tt) << 10) | ((nth * 8 + th) << 5) | (ntw * 8 + tw);
}

// ---------- kernel 1: permute hidden_states rows into tile order (+cast fp32->bf16) ----------
__global__ __launch_bounds__(256) void permute_hs(const float* __restrict__ in,
                                                  unsigned short* __restrict__ out) {
  int cid = blockIdx.x * 256 + threadIdx.x;          // 1,048,576 chunks of 8 elems
  int r = cid >> 7, c = (cid & 127) * 8;
  int s = row_to_seq(r);
  const float* f = in + (size_t)s * 1024 + c;
  u16x8 v;
#pragma unroll
  for (int j = 0; j < 8; ++j) v[j] = f2bf(f[j]);
  *(u16x8*)(out + (size_t)r * 1024 + c) = v;
}

// ---------- kernel 2: transpose the 4 weight matrices [K][N] -> [N][K] (+cast) ----------
__global__ __launch_bounds__(256) void transpose_w(const float* __restrict__ w0,
                                                   const float* __restrict__ w1,
                                                   const float* __restrict__ w2,
                                                   const float* __restrict__ w3,
                                                   unsigned short* __restrict__ out) {
  __shared__ unsigned short Lt[64 * 68];             // [n][k] tile, pad 68
  int m = blockIdx.y;
  const float* W = (m == 0) ? w0 : (m == 1) ? w1 : (m == 2) ? w2 : w3;
  unsigned short* O = out + (size_t)m * 1048576;
  int k0 = (blockIdx.x >> 4) * 64, n0 = (blockIdx.x & 15) * 64;
  int tid = threadIdx.x;
#pragma unroll
  for (int i = 0; i < 2; ++i) {
    int cid = i * 256 + tid;
    int kr = cid >> 3, c = cid & 7;
    const float* f = W + (size_t)(k0 + kr) * 1024 + n0 + c * 8;
#pragma unroll
    for (int j = 0; j < 8; ++j) Lt[(c * 8 + j) * 68 + kr] = f2bf(f[j]);
  }
  __syncthreads();
#pragma unroll
  for (int i = 0; i < 2; ++i) {
    int cid = i * 256 + tid;
    int nr = cid >> 3, c = cid & 7;
    u16x8 v;
#pragma unroll
    for (int j = 0; j < 8; ++j) v[j] = Lt[nr * 68 + c * 8 + j];
    *(u16x8*)(O + (size_t)(n0 + nr) * 1024 + k0 + c * 8) = v;
  }
}

// ---------- gemm_bt: C[M][1024] = (A[M][1024] * Bt[1024][1024]^T) * scale ----------
// 128x128 block tile, BK=64, 4 waves (2x2 of 64x64), XOR-8 swizzled LDS,
// global_load_lds(16B) staging. OUT_F32: final output writes float.
template <int SCATTER, int OUT_F32>
__device__ __forceinline__ void gemm_bt_body(const unsigned short* __restrict__ A,
                                             const unsigned short* __restrict__ Bt,
                                             void* __restrict__ Cv,
                                             int row0, int col0, float scale) {
  __shared__ unsigned short As[128 * 64];
  __shared__ unsigned short Bs[128 * 64];
  const int tid  = threadIdx.x;
  const int lane = tid & 63, w = tid >> 6;
  const int quad = lane >> 4, lm = lane & 15;
  const int wr = (w >> 1) * 64, wc = (w & 1) * 64;
  f32x4 acc[4][4] = {};
  for (int kt = 0; kt < 16; ++kt) {
    const int k0 = kt * 64;
    __syncthreads();
#pragma unroll
    for (int i = 0; i < 4; ++i) {
      int cid = i * 256 + tid;
      int r = cid >> 3, c = cid & 7;
      int cg = c ^ (r & 7);                          // swizzle on SOURCE address
      int base = (i * 256 + (tid & 192)) * 8;        // wave-uniform LDS dst (u16)
      GLOAD_LDS16(A  + (size_t)(row0 + r) * 1024 + k0 + cg * 8, As + base);
      GLOAD_LDS16(Bt + (size_t)(col0 + r) * 1024 + k0 + cg * 8, Bs + base);
    }
    __syncthreads();
#pragma unroll
    for (int kh = 0; kh < 2; ++kh) {
      short8 af[4], bf[4];
#pragma unroll
      for (int t = 0; t < 4; ++t) {
        int ca = (kh * 4 + quad) ^ (lm & 7);
        af[t] = *(const short8*)(As + (wr + t * 16 + lm) * 64 + ca * 8);
        bf[t] = *(const short8*)(Bs + (wc + t * 16 + lm) * 64 + ca * 8);
      }
#pragma unroll
      for (int rt = 0; rt < 4; ++rt)
#pragma unroll
        for (int ct = 0; ct < 4; ++ct)
          acc[rt][ct] = MFMA_BF16(af[rt], bf[ct], acc[rt][ct]);
    }
  }
#pragma unroll
  for (int rt = 0; rt < 4; ++rt)
#pragma unroll
    for (int ct = 0; ct < 4; ++ct)
#pragma unroll
      for (int g = 0; g < 4; ++g) {
        int R  = row0 + wr + rt * 16 + quad * 4 + g;
        int Cc = col0 + wc + ct * 16 + lm;
        int Rs = SCATTER ? row_to_seq(R) : R;
        float vv = acc[rt][ct][g] * scale;
        if (OUT_F32) ((float*)Cv)[(size_t)Rs * 1024 + Cc] = vv;
        else ((unsigned short*)Cv)[(size_t)Rs * 1024 + Cc] = f2bf(vv);
      }
}

// ---------- gemm_qkv3: the 3 QKV GEMMs fused, SHARED A-staging ----------
// All three read the same A (HSt). One block: A-tile 128x64 staged once per
// k-step + three 64x64 B-tiles (one per weight matrix) -> 48 MFMA per k-step
// per wave vs 32 for the split version, with 10 gloads (vs 8) and 20 ds_reads
// (vs 16): MFMA:stage ratio +50%, MFMA:ds_read +20%, barrier amortization +50%.
// Per-wave tile 64x32 per matrix; acc = 3x4x2 f32x4 = 96 VGPR (total ~160,
// the GEMM envelope that m97 ran at — NOT attn's 64-reg envelope).
// LDS: As 16 KB + 3x Bs 8 KB = 40 KB. Grid dim3(16,64) = 1024 blocks.
__global__ __launch_bounds__(256) void gemm_qkv3(const unsigned short* __restrict__ A,
                                                 const unsigned short* __restrict__ Wt,
                                                 unsigned short* __restrict__ QKV) {
  __shared__ unsigned short As[128 * 64];
  __shared__ unsigned short Bs[3][64 * 64];
  const int tid  = threadIdx.x;
  const int lane = tid & 63, w = tid >> 6;
  const int quad = lane >> 4, lm = lane & 15;
  const int wr = (w >> 1) * 64, wc = (w & 1) * 32;   // wave tile 64x32
  const int row0 = blockIdx.y * 128, col0 = blockIdx.x * 64;
  f32x4 acc[3][4][2] = {};
  for (int kt = 0; kt < 16; ++kt) {
    const int k0 = kt * 64;
    __syncthreads();
#pragma unroll
    for (int i = 0; i < 4; ++i) {                    // stage A (4 passes)
      int cid = i * 256 + tid;
      int r = cid >> 3, c = cid & 7;
      int cg = c ^ (r & 7);
      int base = (i * 256 + (tid & 192)) * 8;
      GLOAD_LDS16(A + (size_t)(row0 + r) * 1024 + k0 + cg * 8, As + base);
    }
#pragma unroll
    for (int m = 0; m < 3; ++m)                      // stage 3 B tiles (2 passes each)
#pragma unroll
      for (int i = 0; i < 2; ++i) {
        int cid = i * 256 + tid;
        int r = cid >> 3, c = cid & 7;
        int cg = c ^ (r & 7);
        int base = (i * 256 + (tid & 192)) * 8;
        GLOAD_LDS16(Wt + (size_t)m * 1048576 + (size_t)(col0 + r) * 1024 + k0 + cg * 8,
                    Bs[m] + base);
      }
    __syncthreads();
#pragma unroll
    for (int kh = 0; kh < 2; ++kh) {
      const int ca = (kh * 4 + quad) ^ (lm & 7);
      short8 af[4], bf[3][2];
#pragma unroll
      for (int t = 0; t < 4; ++t)
        af[t] = *(const short8*)(As + (wr + t * 16 + lm) * 64 + ca * 8);
#pragma unroll
      for (int m = 0; m < 3; ++m)
#pragma unroll
        for (int u = 0; u < 2; ++u)
          bf[m][u] = *(const short8*)(Bs[m] + (wc + u * 16 + lm) * 64 + ca * 8);
#pragma unroll
      for (int m = 0; m < 3; ++m)
#pragma unroll
        for (int t = 0; t < 4; ++t)
#pragma unroll
          for (int u = 0; u < 2; ++u)
            acc[m][t][u] = MFMA_BF16(af[t], bf[m][u], acc[m][t][u]);
    }
  }
#pragma unroll
  for (int m = 0; m < 3; ++m) {
    // fold softmax scale (1/8)*log2(e) into Q so attn's exp2 needs no multiply
    const float scale = (m == 0) ? 0.18033688011112042f : 1.0f;
    unsigned short* Cm = QKV + (size_t)m * 8388608;
#pragma unroll
    for (int t = 0; t < 4; ++t)
#pragma unroll
      for (int u = 0; u < 2; ++u)
#pragma unroll
        for (int g = 0; g < 4; ++g) {
          int R  = row0 + wr + t * 16 + quad * 4 + g;
          int Cc = col0 + wc + u * 16 + lm;
          Cm[(size_t)R * 1024 + Cc] = f2bf(acc[m][t][u][g] * scale);
        }
  }
}

__global__ __launch_bounds__(256) void gemm_out(const unsigned short* __restrict__ A,
                                                const unsigned short* __restrict__ Wt,
                                                float* __restrict__ Cout) {
  gemm_bt_body<1, 1>(A, Wt, Cout, blockIdx.y * 128, blockIdx.x * 128, 1.0f);
}

// ---------- kernel: V [8192][16*64] (tile rows) -> Vt [16][64][8192] ----------
__global__ __launch_bounds__(256) void transpose_v(const unsigned short* __restrict__ V,
                                                   unsigned short* __restrict__ Vt) {
  __shared__ unsigned short Lt[64 * 136];            // [d][r] tile, pad 136
  int kt = blockIdx.x, h = blockIdx.y, tid = threadIdx.x;
#pragma unroll
  for (int i = 0; i < 4; ++i) {
    int cid = i * 256 + tid;                         // 1024 chunks
    int r = cid >> 3, c = cid & 7;
    u16x8 v = *(const u16x8*)(V + (size_t)(kt * 128 + r) * 1024 + h * 64 + c * 8);
#pragma unroll
    for (int j = 0; j < 8; ++j) Lt[(c * 8 + j) * 136 + r] = v[j];
  }
  __syncthreads();
#pragma unroll
  for (int i = 0; i < 4; ++i) {
    int cid = i * 256 + tid;
    int d = cid >> 4, c = cid & 15;
    u16x8 v = *(const u16x8*)(Lt + d * 136 + c * 8);
    *(u16x8*)(Vt + (size_t)(h * 64 + d) * 8192 + kt * 128 + c * 8) = v;
  }
}

// ---------- attention: one block per (head, q-tile), 512 threads (8 waves) ----------
// (unchanged from round 7 — kept byte-identical to isolate the GEMM change)
// DOUBLE-BUFFERED K and V -> ONE barrier per kv iteration. Per iter: issue
// K[it+1],V[it+1] into buf[1-p] at the TOP, compute from buf[p], one end
// barrier drains vmcnt + licenses overwriting buf[p].
// VALU trim: precomputed per-lane staging offsets, v_cvt_pk_bf16_f32 P-pack.
// LDS: Ks 32 + Vs 32 + Pb 16 = 80 KB -> 2 blocks/CU.
// (512,4): allocator settles at <=64 VGPR here; bigger live sets spill 10x.
__global__ __launch_bounds__(512, 4) void attn(const unsigned short* __restrict__ Q,
                                               const unsigned short* __restrict__ K,
                                               const unsigned short* __restrict__ Vt,
                                               unsigned short* __restrict__ O) {
  __shared__ unsigned short Ks[2][128 * 64];         // 32 KB [kv][d], swizzled
  __shared__ unsigned short Vs[2][64 * 128];         // 32 KB [d][kv], swizzled
  __shared__ unsigned short Pb[8 * 16 * 64];         // 16 KB: per-wave 2 KB P slice

  const int tid  = threadIdx.x;
  const int lane = tid & 63, w = tid >> 6;           // w in 0..7
  const int quad = lane >> 4, lm = lane & 15;
  unsigned short* Pbw = Pb + w * 1024;               // wave-private [q 16][kv 64]

  const int h = blockIdx.x >> 6, qt = blockIdx.x & 63;
  const int ntt = qt >> 4, nth = (qt >> 2) & 3, ntw = qt & 3;
  const int kt0 = min(max(ntt, 1), 2) - 1;           // t-window start tile
  const int kh0 = min(max(nth, 1), 3) - 1;
  const int kw0 = min(max(ntw, 1), 3) - 1;

  // per-lane invariant staging offsets (u32 element offsets)
  const int cid1 = 512 + tid;
  const int rK0 = tid  >> 3, cgK0 = (tid  & 7) ^ (rK0 & 7);
  const int rK1 = cid1 >> 3, cgK1 = (cid1 & 7) ^ (rK1 & 7);
  const unsigned koff0 = rK0 * 1024 + h * 64 + cgK0 * 8;
  const unsigned koff1 = rK1 * 1024 + h * 64 + cgK1 * 8;
  const int dV0 = tid  >> 4, cgV0 = (tid  & 15) ^ (dV0 & 7);
  const int dV1 = cid1 >> 4, cgV1 = (cid1 & 15) ^ (dV1 & 7);
  const unsigned voff0 = (h * 64 + dV0) * 8192 + cgV0 * 8;
  const unsigned voff1 = (h * 64 + dV1) * 8192 + cgV1 * 8;
  const unsigned ldsD0 = (tid & 448) * 8;            // wave-uniform LDS dst (u16)
  const unsigned ldsD1 = (512 + (tid & 448)) * 8;

  // Q B-frags (Q pre-scaled by CSC): n=q = w*16+lm, k=d = kh*32+quad*8+j
  short8 bq[2];
#pragma unroll
  for (int kh = 0; kh < 2; ++kh)
    bq[kh] = *(const short8*)(Q + (size_t)(qt * 128 + w * 16 + lm) * 1024
                                + h * 64 + kh * 32 + quad * 8);

  short8 ones8;
#pragma unroll
  for (int j = 0; j < 8; ++j) ones8[j] = (short)0x3F80;   // bf16 1.0

  f32x4 o_acc[4] = {};                               // [d-tile]
  f32x4 l_acc = {};                                  // row sums of P

  // ---- prologue: stage K[0], V[0] into buf 0, drain, barrier ----
  {
    const int kvt0 = kt0 * 16 + kh0 * 4 + kw0;
    const unsigned k0 = (unsigned)kvt0 << 17;
    const unsigned v0 = (unsigned)kvt0 << 7;
    GLOAD_LDS16(K  + koff0 + k0, Ks[0] + ldsD0);
    GLOAD_LDS16(K  + koff1 + k0, Ks[0] + ldsD1);
    GLOAD_LDS16(Vt + voff0 + v0, Vs[0] + ldsD0);
    GLOAD_LDS16(Vt + voff1 + v0, Vs[0] + ldsD1);
  }
  __syncthreads();                                   // K[0],V[0] landed

  for (int it = 0; it < 12; ++it) {
    const int p = it & 1;
    const unsigned short* Ksp = Ks[p];
    const unsigned short* Vsp = Vs[p];

    // issue K[it+1],V[it+1] into buf[1-p]; in flight across this whole iter.
    if (it < 11) {
      const int jt = it + 1;
      const int t2 = jt >> 2, h2 = (jt >> 1) & 1, w2 = jt & 1;
      const int kvn = (kt0 + t2) * 16 + (kh0 + h2) * 4 + (kw0 + w2);
      const unsigned kn = (unsigned)kvn << 17;
      const unsigned vn = (unsigned)kvn << 7;
      GLOAD_LDS16(K  + koff0 + kn, Ks[1 - p] + ldsD0);
      GLOAD_LDS16(K  + koff1 + kn, Ks[1 - p] + ldsD1);
      GLOAD_LDS16(Vt + voff0 + vn, Vs[1 - p] + ldsD0);
      GLOAD_LDS16(Vt + voff1 + vn, Vs[1 - p] + ldsD1);
    }

    // S^T[kv 128][q 16(wave)] = K * Q^T
    f32x4 sa[8] = {};                                // [kv-tile rt]
#pragma unroll
    for (int kh = 0; kh < 2; ++kh) {
      short8 ak[8];
#pragma unroll
      for (int rt = 0; rt < 8; ++rt)
        ak[rt] = *(const short8*)(Ksp + (rt * 16 + lm) * 64 + (((kh * 4 + quad) ^ (lm & 7)) * 8));
      __builtin_amdgcn_s_setprio(1);
#pragma unroll
      for (int rt = 0; rt < 8; ++rt)
        sa[rt] = MFMA_BF16(ak[rt], bq[kh], sa[rt]);
      __builtin_amdgcn_s_setprio(0);
    }

    // P = exp2(S^T) packed to bf16 pairs (registers)
    u32x2 pk[8];
#pragma unroll
    for (int rt = 0; rt < 8; ++rt) {
      pk[rt][0] = pack2bf(exp2f(sa[rt][0]), exp2f(sa[rt][1]));
      pk[rt][1] = pack2bf(exp2f(sa[rt][2]), exp2f(sa[rt][3]));
    }

    // O += P * V ; l += P * 1  — two kv-halves through the 2 KB Pb slice.
#pragma unroll
    for (int half = 0; half < 2; ++half) {
#pragma unroll
      for (int rt4 = 0; rt4 < 4; ++rt4) {
        *(u32x2*)(Pbw + lm * 64 + (((rt4 * 2 + (quad >> 1)) ^ (lm & 7)) * 8) + (quad & 1) * 4)
            = pk[half * 4 + rt4];
      }
#pragma unroll
      for (int ks2 = 0; ks2 < 2; ++ks2) {
        short8 ap = *(const short8*)(Pbw + lm * 64 + (((ks2 * 4 + quad) ^ (lm & 7)) * 8));
        const int ks = half * 2 + ks2;
        short8 bv[4];
#pragma unroll
        for (int nt = 0; nt < 4; ++nt)
          bv[nt] = *(const short8*)(Vsp + (nt * 16 + lm) * 128 + (((ks * 4 + quad) ^ (lm & 7)) * 8));
        __builtin_amdgcn_s_setprio(1);
        l_acc = MFMA_BF16(ap, ones8, l_acc);
#pragma unroll
        for (int nt = 0; nt < 4; ++nt)
          o_acc[nt] = MFMA_BF16(ap, bv[nt], o_acc[nt]);
        __builtin_amdgcn_s_setprio(0);
      }
    }

    // ONE barrier: drains vmcnt (buf[1-p] staged) and licenses overwriting buf[p].
    __syncthreads();
  }

  // normalize by l and store (rows q = quad*4+g -> per-lane l)
#pragma unroll
  for (int g = 0; g < 4; ++g) {
    float inv = 1.0f / l_acc[g];
#pragma unroll
    for (int nt = 0; nt < 4; ++nt) {
      int R = qt * 128 + w * 16 + quad * 4 + g;
      O[(size_t)R * 1024 + h * 64 + nt * 16 + lm] = f2bf(o_acc[nt][g] * inv);
    }
  }
}

// ---------- host ----------
extern "C" void kernel_launch(void* const* d_in, const int* in_sizes, int n_in,
                              void* d_out, int out_size, void* d_ws, size_t ws_size,
                              hipStream_t stream) {
  const float* hs = (const float*)d_in[0];
  const float* wq = (const float*)d_in[1];
  const float* wk = (const float*)d_in[2];
  const float* wv = (const float*)d_in[3];
  const float* wo = (const float*)d_in[4];
  float* out = (float*)d_out;                        // reference output dtype = float32

  const size_t NEL = 8388608;                        // 8192*1024
  unsigned short* ws  = (unsigned short*)d_ws;
  unsigned short* HSt = ws;                          // [8192][1024] tile-ordered
  unsigned short* Qb  = ws + 1 * NEL;
  unsigned short* Kb  = ws + 2 * NEL;
  unsigned short* Vb  = ws + 3 * NEL;
  unsigned short* Vtb = ws + 4 * NEL;                // [16][64][8192]
  unsigned short* Ot  = ws + 5 * NEL;
  unsigned short* Wt  = ws + 6 * NEL;                // 4 x [1024][1024] transposed
  if (ws_size < (6 * NEL + 4 * 1048576) * sizeof(unsigned short)) return;

  permute_hs<<<4096, 256, 0, stream>>>(hs, HSt);
  transpose_w<<<dim3(256, 4), 256, 0, stream>>>(wq, wk, wv, wo, Wt);
  gemm_qkv3<<<dim3(16, 64), 256, 0, stream>>>(HSt, Wt, Qb);
  transpose_v<<<dim3(64, 16), 256, 0, stream>>>(Vb, Vtb);
  attn<<<1024, 512, 0, stream>>>(Qb, Kb, Vtb, Ot);
  gemm_out<<<dim3(8, 64, 1), 256, 0, stream>>>(Ot, Wt + 3 * 1048576, out);
  (void)in_sizes; (void)n_in; (void)out_size;
}